// Round 4
// baseline (487.660 us; speedup 1.0000x reference)
//
#include <hip/hip_runtime.h>

// Window attention: B=4096, L=49, C=256, H=8, D=32
// prep : weight swizzle (bf16 MFMA frag order) + bias table
// kall : fully fused qkv GEMM + attention + proj, one block per window.
//
// Q,K computed TRANSPOSED (C' = W^T x^T -> lane holds [m=lane][d=reg]),
// V computed normal (lane holds [m=reg][d=lane]). Symmetric k-remap
// kappa(g,j) = 16*(j>>2) + 4*g + (j&3) applied to BOTH operands of QK^T and
// PV makes every attention MFMA operand an in-lane repack of GEMM
// accumulators: q/k/v never touch LDS.
//
// Round-3 changes (spill elimination):
//  - __launch_bounds__(256,3): VGPR budget ~170 (combined-GEMM live set ~150)
//    round 2's (256,2)=128 regs forced ~270MB of scratch traffic.
//  - xs/osd share one LDS union (33.8KB): xs dead before osd is born.
//  - O for both head-passes kept packed bf16x2 in 32 u32 regs until after
//    the last xs read; then sync -> osd -> sync -> proj. 3 barriers total.

typedef short s8v __attribute__((ext_vector_type(8)));   // 8 bf16 (4 VGPRs)
typedef short s4v __attribute__((ext_vector_type(4)));   // 4 bf16 (8B)
typedef float f4  __attribute__((ext_vector_type(4)));   // MFMA C/D frag

#define MFMA(a,b,c) __builtin_amdgcn_mfma_f32_16x16x32_bf16((a),(b),(c),0,0,0)

__device__ __forceinline__ unsigned short f2bf(float f) {
    unsigned u = __float_as_uint(f);
    u = u + 0x7fffu + ((u >> 16) & 1u);   // round-to-nearest-even
    return (unsigned short)(u >> 16);
}

// ---------------- prep: weight swizzle + bias table ----------------
// wq layout: [nt=48][ks=8][lane=64][j=8]; element = qkv_w[ks*32+(lane>>4)*8+j][nt*16+(lane&15)]
// (serves as B-frag for normal GEMM and A-frag for transposed GEMM)
// wp: same with nt=16 over proj_w
// biasT: [h=8][key=64][query=64] fp32, -1e30 for key>=49 or query>=49
__global__ void prep(const float* __restrict__ qkv_w, const float* __restrict__ proj_w,
                     const float* __restrict__ rel_bias, const int* __restrict__ rel_idx,
                     unsigned short* __restrict__ wq, unsigned short* __restrict__ wp,
                     float* __restrict__ biasT)
{
    int idx = blockIdx.x * blockDim.x + threadIdx.x;
    int stride = gridDim.x * blockDim.x;
    for (int i = idx; i < 48*8*64*8; i += stride) {
        int j = i & 7, l = (i >> 3) & 63, ks = (i >> 9) & 7, nt = i >> 12;
        int k = ks*32 + (l >> 4)*8 + j;
        int n = nt*16 + (l & 15);
        wq[i] = f2bf(qkv_w[k*768 + n]);
    }
    for (int i = idx; i < 16*8*64*8; i += stride) {
        int j = i & 7, l = (i >> 3) & 63, ks = (i >> 9) & 7, nt = i >> 12;
        int k = ks*32 + (l >> 4)*8 + j;
        int n = nt*16 + (l & 15);
        wp[i] = f2bf(proj_w[k*256 + n]);
    }
    for (int i = idx; i < 8*64*64; i += stride) {
        int q = i & 63, m = (i >> 6) & 63, h = i >> 12;
        float v = -1e30f;
        if (m < 49 && q < 49) v = rel_bias[rel_idx[q*49 + m]*8 + h];
        biasT[i] = v;
    }
}

// ---------------- kall: fused qkv + attention + proj ----------------
__global__ __launch_bounds__(256, 3) void kall(
    const float* __restrict__ x, const float* __restrict__ qkv_b,
    const unsigned short* __restrict__ wq, const float* __restrict__ biasT,
    const unsigned short* __restrict__ wp, const float* __restrict__ proj_b,
    float* __restrict__ out)
{
    __shared__ __align__(16) union SMem {
        unsigned short xs[4][8][64][8];    // x frags, 32768 B (QKV phase)
        unsigned short osd[64][264];       // O bf16 row-major, 33792 B (proj phase)
    } sm;

    const int b    = blockIdx.x;
    const int tid  = threadIdx.x;
    const int w    = tid >> 6;
    const int lane = tid & 63;
    const int ln   = lane & 15;
    const int g    = lane >> 4;

    // ---- stage x -> frag-layout bf16 LDS ----
    const float* xb = x + (size_t)b * (49*256);
    for (int i = tid; i < 4096; i += 256) {
        int r = i >> 6, c4 = i & 63;
        float4 v = make_float4(0.f, 0.f, 0.f, 0.f);
        if (r < 49) v = ((const float4*)xb)[r*64 + c4];
        s4v o;
        o[0] = (short)f2bf(v.x); o[1] = (short)f2bf(v.y);
        o[2] = (short)f2bf(v.z); o[3] = (short)f2bf(v.w);
        int mt = r >> 4, lnr = r & 15;
        int c  = c4 * 4;
        int ks = c >> 5, gg = (c >> 3) & 3, j0 = c & 7;
        *(s4v*)&sm.xs[mt][ks][gg*16 + lnr][j0] = o;
    }
    __syncthreads();

    const float scale = 0.17677669529663687f;  // 1/sqrt(32)

    unsigned opk[2][16];                       // O both passes, bf16-pair packed

    #pragma unroll
    for (int p = 0; p < 2; ++p) {
        const int h = 2*w + p;                 // this wave's head for this pass

        // ---- QKV GEMM ----
        // qa/ka (transposed): qa[dh][mt][r] = Q[m=mt*16+ln][d=dh*16+g*4+r]
        // va (normal):        va[mt][dh][r] = V[m=mt*16+g*4+r][d=dh*16+ln]
        f4 qa[2][4], ka[2][4], va[4][2];
        #pragma unroll
        for (int dh = 0; dh < 2; ++dh)
            #pragma unroll
            for (int mt = 0; mt < 4; ++mt) {
                qa[dh][mt] = (f4){0.f,0.f,0.f,0.f};
                ka[dh][mt] = (f4){0.f,0.f,0.f,0.f};
                va[mt][dh] = (f4){0.f,0.f,0.f,0.f};
            }

        #pragma unroll
        for (int ks = 0; ks < 8; ++ks) {
            s8v xf[4];
            #pragma unroll
            for (int mt = 0; mt < 4; ++mt)
                xf[mt] = *(const s8v*)&sm.xs[mt][ks][lane][0];
            s8v wfq[2], wfk[2], wfv[2];
            #pragma unroll
            for (int dh = 0; dh < 2; ++dh) {
                wfq[dh] = *(const s8v*)&wq[(size_t)((( 2*h+dh)*8 + ks)*64 + lane) * 8];
                wfk[dh] = *(const s8v*)&wq[(size_t)(((16+2*h+dh)*8 + ks)*64 + lane) * 8];
                wfv[dh] = *(const s8v*)&wq[(size_t)(((32+2*h+dh)*8 + ks)*64 + lane) * 8];
            }
            #pragma unroll
            for (int dh = 0; dh < 2; ++dh)
                #pragma unroll
                for (int mt = 0; mt < 4; ++mt) {
                    qa[dh][mt] = MFMA(wfq[dh], xf[mt], qa[dh][mt]);   // transposed
                    ka[dh][mt] = MFMA(wfk[dh], xf[mt], ka[dh][mt]);
                    va[mt][dh] = MFMA(xf[mt], wfv[dh], va[mt][dh]);   // normal
                }
        }

        // ---- biases ----
        float4 bq[2], bk[2]; float bv[2];
        #pragma unroll
        for (int dh = 0; dh < 2; ++dh) {
            bq[dh] = *(const float4*)&qkv_b[       h*32 + dh*16 + g*4];
            bk[dh] = *(const float4*)&qkv_b[256 +  h*32 + dh*16 + g*4];
            bv[dh] = qkv_b[512 + h*32 + dh*16 + ln];
        }

        // ---- in-lane repack to bf16 frags (kappa mapping) ----
        s8v qf[4], kf[4], vf[2][2];
        #pragma unroll
        for (int t = 0; t < 4; ++t)
            #pragma unroll
            for (int j = 0; j < 8; ++j) {
                int dh = j >> 2, r = j & 3;
                qf[t][j] = (short)f2bf((qa[dh][t][r] + ((const float*)&bq[dh])[r]) * scale);
                kf[t][j] = (short)f2bf( ka[dh][t][r] + ((const float*)&bk[dh])[r]);
            }
        #pragma unroll
        for (int ksp = 0; ksp < 2; ++ksp)
            #pragma unroll
            for (int dh = 0; dh < 2; ++dh)
                #pragma unroll
                for (int j = 0; j < 8; ++j)
                    vf[ksp][dh][j] = (short)f2bf(va[2*ksp + (j>>2)][dh][j & 3] + bv[dh]);

        // ---- attention (per query tile) ----
        #pragma unroll
        for (int qt = 0; qt < 4; ++qt) {
            f4 st[4];
            #pragma unroll
            for (int kt = 0; kt < 4; ++kt) {
                f4 z = (f4){0.f,0.f,0.f,0.f};
                st[kt] = MFMA(kf[kt], qf[qt], z);
            }
            float pr[16];
            float mx = -3.0e38f;
            #pragma unroll
            for (int kt = 0; kt < 4; ++kt)
                #pragma unroll
                for (int r = 0; r < 4; ++r) {
                    float s = st[kt][r] + biasT[(h*64 + kt*16 + g*4 + r)*64 + qt*16 + ln];
                    pr[kt*4 + r] = s;
                    mx = fmaxf(mx, s);
                }
            mx = fmaxf(mx, __shfl_xor(mx, 16));
            mx = fmaxf(mx, __shfl_xor(mx, 32));
            float sum = 0.f;
            #pragma unroll
            for (int i = 0; i < 16; ++i) {
                float e = __expf(pr[i] - mx);
                pr[i] = e;
                sum += e;
            }
            sum += __shfl_xor(sum, 16);
            sum += __shfl_xor(sum, 32);
            float rinv = 1.f / sum;

            s8v pa[2];
            #pragma unroll
            for (int ksp = 0; ksp < 2; ++ksp)
                #pragma unroll
                for (int j = 0; j < 8; ++j)
                    pa[ksp][j] = (short)f2bf(pr[8*ksp + 4*(j>>2) + (j&3)] * rinv);

            f4 oacc[2];
            oacc[0] = (f4){0.f,0.f,0.f,0.f};
            oacc[1] = (f4){0.f,0.f,0.f,0.f};
            #pragma unroll
            for (int ksp = 0; ksp < 2; ++ksp)
                #pragma unroll
                for (int dh = 0; dh < 2; ++dh)
                    oacc[dh] = MFMA(pa[ksp], vf[ksp][dh], oacc[dh]);

            // pack O tile to bf16 pairs (2 regs per dh)
            #pragma unroll
            for (int dh = 0; dh < 2; ++dh)
                #pragma unroll
                for (int rp = 0; rp < 2; ++rp)
                    opk[p][qt*4 + dh*2 + rp] =
                        (unsigned)f2bf(oacc[dh][2*rp]) |
                        ((unsigned)f2bf(oacc[dh][2*rp+1]) << 16);
        }
    }

    // ---- all xs reads done; repurpose LDS as osd ----
    __syncthreads();
    #pragma unroll
    for (int p = 0; p < 2; ++p) {
        int h = 2*w + p;
        #pragma unroll
        for (int qt = 0; qt < 4; ++qt)
            #pragma unroll
            for (int dh = 0; dh < 2; ++dh)
                #pragma unroll
                for (int r = 0; r < 4; ++r)
                    sm.osd[qt*16 + g*4 + r][h*32 + dh*16 + ln] =
                        (unsigned short)(opk[p][qt*4 + dh*2 + (r>>1)] >> (16*(r&1)));
    }
    __syncthreads();

    // ---- proj GEMM: out = O @ Wp + b ----
    f4 acc[4][4];
    #pragma unroll
    for (int mt = 0; mt < 4; ++mt)
        #pragma unroll
        for (int t = 0; t < 4; ++t)
            acc[mt][t] = (f4){0.f,0.f,0.f,0.f};

    #pragma unroll
    for (int ks = 0; ks < 8; ++ks) {
        s8v av[4], bw[4];
        #pragma unroll
        for (int mt = 0; mt < 4; ++mt)
            av[mt] = *(const s8v*)&sm.osd[mt*16 + ln][ks*32 + g*8];
        #pragma unroll
        for (int t = 0; t < 4; ++t) {
            int nt = w*4 + t;
            bw[t] = *(const s8v*)&wp[(size_t)((nt*8 + ks)*64 + lane) * 8];
        }
        #pragma unroll
        for (int mt = 0; mt < 4; ++mt)
            #pragma unroll
            for (int t = 0; t < 4; ++t)
                acc[mt][t] = MFMA(av[mt], bw[t], acc[mt][t]);
    }

    float* ob = out + (size_t)b * (49*256);
    #pragma unroll
    for (int t = 0; t < 4; ++t) {
        int n = (w*4 + t)*16 + ln;
        float pb = proj_b[n];
        #pragma unroll
        for (int mt = 0; mt < 4; ++mt)
            #pragma unroll
            for (int r = 0; r < 4; ++r) {
                int q = mt*16 + g*4 + r;
                if (q < 49)
                    ob[q*256 + n] = acc[mt][t][r] + pb;
            }
    }
}

extern "C" void kernel_launch(void* const* d_in, const int* in_sizes, int n_in,
                              void* d_out, int out_size, void* d_ws, size_t ws_size,
                              hipStream_t stream)
{
    (void)n_in; (void)out_size; (void)ws_size;
    const float* x        = (const float*)d_in[0];
    const int*   rel_idx  = (const int*)  d_in[1];
    const float* qkv_w    = (const float*)d_in[2];
    const float* qkv_b    = (const float*)d_in[3];
    const float* rel_bias = (const float*)d_in[4];
    const float* proj_w   = (const float*)d_in[5];
    const float* proj_b   = (const float*)d_in[6];
    float* out = (float*)d_out;

    const int B = in_sizes[0] / (49*256);

    unsigned short* wq = (unsigned short*)d_ws;                     // 393216 B
    unsigned short* wp = wq + 48*8*64*8;                            // 131072 B
    float* biasT = (float*)((char*)d_ws + 524288);                  // 131072 B

    prep<<<256, 256, 0, stream>>>(qkv_w, proj_w, rel_bias, rel_idx, wq, wp, biasT);
    kall<<<B, 256, 0, stream>>>(x, qkv_b, wq, biasT, wp, proj_b, out);
}

// Round 5
// 417.107 us; speedup vs baseline: 1.1691x; 1.1691x over previous
//
#include <hip/hip_runtime.h>

// Window attention: B=4096, L=49, C=256, H=8, D=32
// prep : weight swizzle (bf16 MFMA frag order) + bias table
// kall : fully fused qkv GEMM + attention + proj; one block (512 thr, 8 waves)
//        per window, ONE HEAD PER WAVE (no multi-pass register blowup).
//
// Q,K computed TRANSPOSED (C' = W^T x^T -> lane holds [m=lane][d=reg]),
// V computed normal (lane holds [m=reg][d=lane]). Symmetric k-remap
// kappa(g,j) = 16*(j>>2) + 4*g + (j&3) applied to BOTH operands of QK^T and
// PV makes every attention MFMA operand an in-lane repack of GEMM
// accumulators: q/k/v never touch LDS.
//
// Round-4 changes (vs R3's spilling 2-pass version):
//  - 8 waves, h = wave id: per-wave live set ~130 VGPR -> no spills
//    (R3/R2 spilled ~300MB+ of scratch traffic; VGPR_Count=84 w/ huge WRITE).
//  - xs lane index XOR-swizzled by ks: stage-write banks uniform (was 16-way
//    conflict -> 9.4M conflict cycles); frag read stays a lane permutation.
//  - osd separate from xs (66KB total LDS, 2 blocks/CU): O written right
//    after attention, only 2 barriers per block.

typedef short s8v __attribute__((ext_vector_type(8)));   // 8 bf16 (4 VGPRs)
typedef short s4v __attribute__((ext_vector_type(4)));   // 4 bf16 (8B)
typedef float f4  __attribute__((ext_vector_type(4)));   // MFMA C/D frag

#define MFMA(a,b,c) __builtin_amdgcn_mfma_f32_16x16x32_bf16((a),(b),(c),0,0,0)

__device__ __forceinline__ unsigned short f2bf(float f) {
    unsigned u = __float_as_uint(f);
    u = u + 0x7fffu + ((u >> 16) & 1u);   // round-to-nearest-even
    return (unsigned short)(u >> 16);
}

// ---------------- prep: weight swizzle + bias table ----------------
// wq layout: [nt=48][ks=8][lane=64][j=8]; element = qkv_w[ks*32+(lane>>4)*8+j][nt*16+(lane&15)]
// (serves as B-frag for normal GEMM and A-frag for transposed GEMM)
// wp: same with nt=16 over proj_w
// biasT: [h=8][key=64][query=64] fp32, -1e30 for key>=49 or query>=49
__global__ void prep(const float* __restrict__ qkv_w, const float* __restrict__ proj_w,
                     const float* __restrict__ rel_bias, const int* __restrict__ rel_idx,
                     unsigned short* __restrict__ wq, unsigned short* __restrict__ wp,
                     float* __restrict__ biasT)
{
    int idx = blockIdx.x * blockDim.x + threadIdx.x;
    int stride = gridDim.x * blockDim.x;
    for (int i = idx; i < 48*8*64*8; i += stride) {
        int j = i & 7, l = (i >> 3) & 63, ks = (i >> 9) & 7, nt = i >> 12;
        int k = ks*32 + (l >> 4)*8 + j;
        int n = nt*16 + (l & 15);
        wq[i] = f2bf(qkv_w[k*768 + n]);
    }
    for (int i = idx; i < 16*8*64*8; i += stride) {
        int j = i & 7, l = (i >> 3) & 63, ks = (i >> 9) & 7, nt = i >> 12;
        int k = ks*32 + (l >> 4)*8 + j;
        int n = nt*16 + (l & 15);
        wp[i] = f2bf(proj_w[k*256 + n]);
    }
    for (int i = idx; i < 8*64*64; i += stride) {
        int q = i & 63, m = (i >> 6) & 63, h = i >> 12;
        float v = -1e30f;
        if (m < 49 && q < 49) v = rel_bias[rel_idx[q*49 + m]*8 + h];
        biasT[i] = v;
    }
}

// ---------------- kall: fused qkv + attention + proj ----------------
__global__ __launch_bounds__(512, 4) void kall(
    const float* __restrict__ x, const float* __restrict__ qkv_b,
    const unsigned short* __restrict__ wq, const float* __restrict__ biasT,
    const unsigned short* __restrict__ wp, const float* __restrict__ proj_b,
    float* __restrict__ out)
{
    __shared__ __align__(16) unsigned short xs[4][8][64][8];   // x frags, 32768 B (lane^ks swizzled)
    __shared__ __align__(16) unsigned short osd[64][264];      // O bf16 row-major, 33792 B

    const int b    = blockIdx.x;
    const int tid  = threadIdx.x;
    const int w    = tid >> 6;      // wave = head
    const int lane = tid & 63;
    const int ln   = lane & 15;
    const int g    = lane >> 4;

    // ---- stage x -> frag-layout bf16 LDS (lane index XOR ks for bank spread) ----
    const float* xb = x + (size_t)b * (49*256);
    for (int i = tid; i < 4096; i += 512) {
        int r = i >> 6, c4 = i & 63;
        float4 v = make_float4(0.f, 0.f, 0.f, 0.f);
        if (r < 49) v = ((const float4*)xb)[r*64 + c4];
        s4v o;
        o[0] = (short)f2bf(v.x); o[1] = (short)f2bf(v.y);
        o[2] = (short)f2bf(v.z); o[3] = (short)f2bf(v.w);
        int mt = r >> 4, lnr = r & 15;
        int c  = c4 * 4;
        int ks = c >> 5, gg = (c >> 3) & 3, j0 = c & 7;
        *(s4v*)&xs[mt][ks][(gg*16 + lnr) ^ ks][j0] = o;
    }
    __syncthreads();

    const float scale = 0.17677669529663687f;  // 1/sqrt(32)
    const int h = w;                           // this wave's head

    // ---- QKV GEMM ----
    // qa/ka (transposed): qa[dh][mt][r] = Q[m=mt*16+ln][d=dh*16+g*4+r]
    // va (normal):        va[mt][dh][r] = V[m=mt*16+g*4+r][d=dh*16+ln]
    f4 qa[2][4], ka[2][4], va[4][2];
    #pragma unroll
    for (int dh = 0; dh < 2; ++dh)
        #pragma unroll
        for (int mt = 0; mt < 4; ++mt) {
            qa[dh][mt] = (f4){0.f,0.f,0.f,0.f};
            ka[dh][mt] = (f4){0.f,0.f,0.f,0.f};
            va[mt][dh] = (f4){0.f,0.f,0.f,0.f};
        }

    #pragma unroll
    for (int ks = 0; ks < 8; ++ks) {
        s8v xf[4];
        #pragma unroll
        for (int mt = 0; mt < 4; ++mt)
            xf[mt] = *(const s8v*)&xs[mt][ks][lane ^ ks][0];
        s8v wfq[2], wfk[2], wfv[2];
        #pragma unroll
        for (int dh = 0; dh < 2; ++dh) {
            wfq[dh] = *(const s8v*)&wq[(size_t)((( 2*h+dh)*8 + ks)*64 + lane) * 8];
            wfk[dh] = *(const s8v*)&wq[(size_t)(((16+2*h+dh)*8 + ks)*64 + lane) * 8];
            wfv[dh] = *(const s8v*)&wq[(size_t)(((32+2*h+dh)*8 + ks)*64 + lane) * 8];
        }
        #pragma unroll
        for (int dh = 0; dh < 2; ++dh)
            #pragma unroll
            for (int mt = 0; mt < 4; ++mt) {
                qa[dh][mt] = MFMA(wfq[dh], xf[mt], qa[dh][mt]);   // transposed
                ka[dh][mt] = MFMA(wfk[dh], xf[mt], ka[dh][mt]);
                va[mt][dh] = MFMA(xf[mt], wfv[dh], va[mt][dh]);   // normal
            }
    }

    // ---- biases ----
    float4 bq[2], bk[2]; float bv[2];
    #pragma unroll
    for (int dh = 0; dh < 2; ++dh) {
        bq[dh] = *(const float4*)&qkv_b[       h*32 + dh*16 + g*4];
        bk[dh] = *(const float4*)&qkv_b[256 +  h*32 + dh*16 + g*4];
        bv[dh] = qkv_b[512 + h*32 + dh*16 + ln];
    }

    // ---- in-lane repack to bf16 frags (kappa mapping) ----
    s8v qf[4], kf[4], vf[2][2];
    #pragma unroll
    for (int t = 0; t < 4; ++t)
        #pragma unroll
        for (int j = 0; j < 8; ++j) {
            int dh = j >> 2, r = j & 3;
            qf[t][j] = (short)f2bf((qa[dh][t][r] + ((const float*)&bq[dh])[r]) * scale);
            kf[t][j] = (short)f2bf( ka[dh][t][r] + ((const float*)&bk[dh])[r]);
        }
    #pragma unroll
    for (int ksp = 0; ksp < 2; ++ksp)
        #pragma unroll
        for (int dh = 0; dh < 2; ++dh)
            #pragma unroll
            for (int j = 0; j < 8; ++j)
                vf[ksp][dh][j] = (short)f2bf(va[2*ksp + (j>>2)][dh][j & 3] + bv[dh]);

    // ---- attention (per query tile), write O straight to osd ----
    #pragma unroll
    for (int qt = 0; qt < 4; ++qt) {
        f4 st[4];
        #pragma unroll
        for (int kt = 0; kt < 4; ++kt) {
            f4 z = (f4){0.f,0.f,0.f,0.f};
            st[kt] = MFMA(kf[kt], qf[qt], z);
        }
        float pr[16];
        float mx = -3.0e38f;
        #pragma unroll
        for (int kt = 0; kt < 4; ++kt)
            #pragma unroll
            for (int r = 0; r < 4; ++r) {
                float s = st[kt][r] + biasT[(h*64 + kt*16 + g*4 + r)*64 + qt*16 + ln];
                pr[kt*4 + r] = s;
                mx = fmaxf(mx, s);
            }
        mx = fmaxf(mx, __shfl_xor(mx, 16));
        mx = fmaxf(mx, __shfl_xor(mx, 32));
        float sum = 0.f;
        #pragma unroll
        for (int i = 0; i < 16; ++i) {
            float e = __expf(pr[i] - mx);
            pr[i] = e;
            sum += e;
        }
        sum += __shfl_xor(sum, 16);
        sum += __shfl_xor(sum, 32);
        float rinv = 1.f / sum;

        s8v pa[2];
        #pragma unroll
        for (int ksp = 0; ksp < 2; ++ksp)
            #pragma unroll
            for (int j = 0; j < 8; ++j)
                pa[ksp][j] = (short)f2bf(pr[8*ksp + 4*(j>>2) + (j&3)] * rinv);

        f4 oacc[2];
        oacc[0] = (f4){0.f,0.f,0.f,0.f};
        oacc[1] = (f4){0.f,0.f,0.f,0.f};
        #pragma unroll
        for (int ksp = 0; ksp < 2; ++ksp)
            #pragma unroll
            for (int dh = 0; dh < 2; ++dh)
                oacc[dh] = MFMA(pa[ksp], vf[ksp][dh], oacc[dh]);

        #pragma unroll
        for (int dh = 0; dh < 2; ++dh)
            #pragma unroll
            for (int r = 0; r < 4; ++r)
                osd[qt*16 + g*4 + r][h*32 + dh*16 + ln] = f2bf(oacc[dh][r]);
    }
    __syncthreads();

    // ---- proj GEMM: out = O @ Wp + b (2 n-tiles per wave) ----
    f4 acc[4][2];
    #pragma unroll
    for (int mt = 0; mt < 4; ++mt)
        #pragma unroll
        for (int t = 0; t < 2; ++t)
            acc[mt][t] = (f4){0.f,0.f,0.f,0.f};

    #pragma unroll
    for (int ks = 0; ks < 8; ++ks) {
        s8v av[4], bw[2];
        #pragma unroll
        for (int mt = 0; mt < 4; ++mt)
            av[mt] = *(const s8v*)&osd[mt*16 + ln][ks*32 + g*8];
        #pragma unroll
        for (int t = 0; t < 2; ++t) {
            int nt = w*2 + t;
            bw[t] = *(const s8v*)&wp[(size_t)((nt*8 + ks)*64 + lane) * 8];
        }
        #pragma unroll
        for (int mt = 0; mt < 4; ++mt)
            #pragma unroll
            for (int t = 0; t < 2; ++t)
                acc[mt][t] = MFMA(av[mt], bw[t], acc[mt][t]);
    }

    float* ob = out + (size_t)b * (49*256);
    #pragma unroll
    for (int t = 0; t < 2; ++t) {
        int n = (w*2 + t)*16 + ln;
        float pb = proj_b[n];
        #pragma unroll
        for (int mt = 0; mt < 4; ++mt)
            #pragma unroll
            for (int r = 0; r < 4; ++r) {
                int q = mt*16 + g*4 + r;
                if (q < 49)
                    ob[q*256 + n] = acc[mt][t][r] + pb;
            }
    }
}

extern "C" void kernel_launch(void* const* d_in, const int* in_sizes, int n_in,
                              void* d_out, int out_size, void* d_ws, size_t ws_size,
                              hipStream_t stream)
{
    (void)n_in; (void)out_size; (void)ws_size;
    const float* x        = (const float*)d_in[0];
    const int*   rel_idx  = (const int*)  d_in[1];
    const float* qkv_w    = (const float*)d_in[2];
    const float* qkv_b    = (const float*)d_in[3];
    const float* rel_bias = (const float*)d_in[4];
    const float* proj_w   = (const float*)d_in[5];
    const float* proj_b   = (const float*)d_in[6];
    float* out = (float*)d_out;

    const int B = in_sizes[0] / (49*256);

    unsigned short* wq = (unsigned short*)d_ws;                     // 393216 B
    unsigned short* wp = wq + 48*8*64*8;                            // 131072 B
    float* biasT = (float*)((char*)d_ws + 524288);                  // 131072 B

    prep<<<256, 256, 0, stream>>>(qkv_w, proj_w, rel_bias, rel_idx, wq, wp, biasT);
    kall<<<B, 512, 0, stream>>>(x, qkv_b, wq, biasT, wp, proj_b, out);
}

// Round 6
// 313.380 us; speedup vs baseline: 1.5561x; 1.3310x over previous
//
#include <hip/hip_runtime.h>

// Window attention: B=4096, L=49, C=256, H=8, D=32
// prep : weight swizzle (bf16 MFMA frag order) + bias table
// kall : fully fused qkv GEMM + attention + proj; one block (512 thr, 8 waves)
//        per window, ONE HEAD PER WAVE.
//
// Q,K computed TRANSPOSED (C' = W^T x^T -> lane holds [m=lane][d=reg]),
// V computed normal (lane holds [m=reg][d=lane]). Symmetric k-remap
// kappa(g,j) = 16*(j>>2) + 4*g + (j&3) applied to BOTH operands of QK^T and
// PV makes every attention MFMA operand an in-lane repack of GEMM
// accumulators: q/k/v never touch LDS.
//
// Round-5 change: __launch_bounds__(512, 2) -> 256 VGPR cap.
//   R4's (512,4) capped at 128 VGPR < ~150-reg live set (96 acc + 16 xf +
//   24 wf + addr) -> allocator spilled accumulators to scratch: WRITE_SIZE
//   840MB vs 205MB needed. 256-reg cap fits the live set with slack; the
//   resulting 8 waves/CU (2/SIMD) occupancy is fine: only 2 barriers,
//   24 independent MFMA chains per wave, phases wave-local.

typedef short s8v __attribute__((ext_vector_type(8)));   // 8 bf16 (4 VGPRs)
typedef short s4v __attribute__((ext_vector_type(4)));   // 4 bf16 (8B)
typedef float f4  __attribute__((ext_vector_type(4)));   // MFMA C/D frag

#define MFMA(a,b,c) __builtin_amdgcn_mfma_f32_16x16x32_bf16((a),(b),(c),0,0,0)

__device__ __forceinline__ unsigned short f2bf(float f) {
    unsigned u = __float_as_uint(f);
    u = u + 0x7fffu + ((u >> 16) & 1u);   // round-to-nearest-even
    return (unsigned short)(u >> 16);
}

// ---------------- prep: weight swizzle + bias table ----------------
// wq layout: [nt=48][ks=8][lane=64][j=8]; element = qkv_w[ks*32+(lane>>4)*8+j][nt*16+(lane&15)]
// (serves as B-frag for normal GEMM and A-frag for transposed GEMM)
// wp: same with nt=16 over proj_w
// biasT: [h=8][key=64][query=64] fp32, -1e30 for key>=49 or query>=49
__global__ void prep(const float* __restrict__ qkv_w, const float* __restrict__ proj_w,
                     const float* __restrict__ rel_bias, const int* __restrict__ rel_idx,
                     unsigned short* __restrict__ wq, unsigned short* __restrict__ wp,
                     float* __restrict__ biasT)
{
    int idx = blockIdx.x * blockDim.x + threadIdx.x;
    int stride = gridDim.x * blockDim.x;
    for (int i = idx; i < 48*8*64*8; i += stride) {
        int j = i & 7, l = (i >> 3) & 63, ks = (i >> 9) & 7, nt = i >> 12;
        int k = ks*32 + (l >> 4)*8 + j;
        int n = nt*16 + (l & 15);
        wq[i] = f2bf(qkv_w[k*768 + n]);
    }
    for (int i = idx; i < 16*8*64*8; i += stride) {
        int j = i & 7, l = (i >> 3) & 63, ks = (i >> 9) & 7, nt = i >> 12;
        int k = ks*32 + (l >> 4)*8 + j;
        int n = nt*16 + (l & 15);
        wp[i] = f2bf(proj_w[k*256 + n]);
    }
    for (int i = idx; i < 8*64*64; i += stride) {
        int q = i & 63, m = (i >> 6) & 63, h = i >> 12;
        float v = -1e30f;
        if (m < 49 && q < 49) v = rel_bias[rel_idx[q*49 + m]*8 + h];
        biasT[i] = v;
    }
}

// ---------------- kall: fused qkv + attention + proj ----------------
__global__ __launch_bounds__(512, 2) void kall(
    const float* __restrict__ x, const float* __restrict__ qkv_b,
    const unsigned short* __restrict__ wq, const float* __restrict__ biasT,
    const unsigned short* __restrict__ wp, const float* __restrict__ proj_b,
    float* __restrict__ out)
{
    __shared__ __align__(16) unsigned short xs[4][8][64][8];   // x frags, 32768 B (lane^ks swizzled)
    __shared__ __align__(16) unsigned short osd[64][264];      // O bf16 row-major, 33792 B

    const int b    = blockIdx.x;
    const int tid  = threadIdx.x;
    const int w    = tid >> 6;      // wave = head
    const int lane = tid & 63;
    const int ln   = lane & 15;
    const int g    = lane >> 4;

    // ---- stage x -> frag-layout bf16 LDS (lane index XOR ks for bank spread) ----
    const float* xb = x + (size_t)b * (49*256);
    for (int i = tid; i < 4096; i += 512) {
        int r = i >> 6, c4 = i & 63;
        float4 v = make_float4(0.f, 0.f, 0.f, 0.f);
        if (r < 49) v = ((const float4*)xb)[r*64 + c4];
        s4v o;
        o[0] = (short)f2bf(v.x); o[1] = (short)f2bf(v.y);
        o[2] = (short)f2bf(v.z); o[3] = (short)f2bf(v.w);
        int mt = r >> 4, lnr = r & 15;
        int c  = c4 * 4;
        int ks = c >> 5, gg = (c >> 3) & 3, j0 = c & 7;
        *(s4v*)&xs[mt][ks][(gg*16 + lnr) ^ ks][j0] = o;
    }
    __syncthreads();

    const float scale = 0.17677669529663687f;  // 1/sqrt(32)
    const int h = w;                           // this wave's head

    // ---- QKV GEMM ----
    // qa/ka (transposed): qa[dh][mt][r] = Q[m=mt*16+ln][d=dh*16+g*4+r]
    // va (normal):        va[mt][dh][r] = V[m=mt*16+g*4+r][d=dh*16+ln]
    f4 qa[2][4], ka[2][4], va[4][2];
    #pragma unroll
    for (int dh = 0; dh < 2; ++dh)
        #pragma unroll
        for (int mt = 0; mt < 4; ++mt) {
            qa[dh][mt] = (f4){0.f,0.f,0.f,0.f};
            ka[dh][mt] = (f4){0.f,0.f,0.f,0.f};
            va[mt][dh] = (f4){0.f,0.f,0.f,0.f};
        }

    #pragma unroll
    for (int ks = 0; ks < 8; ++ks) {
        s8v xf[4];
        #pragma unroll
        for (int mt = 0; mt < 4; ++mt)
            xf[mt] = *(const s8v*)&xs[mt][ks][lane ^ ks][0];
        s8v wfq[2], wfk[2], wfv[2];
        #pragma unroll
        for (int dh = 0; dh < 2; ++dh) {
            wfq[dh] = *(const s8v*)&wq[(size_t)((( 2*h+dh)*8 + ks)*64 + lane) * 8];
            wfk[dh] = *(const s8v*)&wq[(size_t)(((16+2*h+dh)*8 + ks)*64 + lane) * 8];
            wfv[dh] = *(const s8v*)&wq[(size_t)(((32+2*h+dh)*8 + ks)*64 + lane) * 8];
        }
        #pragma unroll
        for (int dh = 0; dh < 2; ++dh)
            #pragma unroll
            for (int mt = 0; mt < 4; ++mt) {
                qa[dh][mt] = MFMA(wfq[dh], xf[mt], qa[dh][mt]);   // transposed
                ka[dh][mt] = MFMA(wfk[dh], xf[mt], ka[dh][mt]);
                va[mt][dh] = MFMA(xf[mt], wfv[dh], va[mt][dh]);   // normal
            }
    }

    // ---- biases ----
    float4 bq[2], bk[2]; float bv[2];
    #pragma unroll
    for (int dh = 0; dh < 2; ++dh) {
        bq[dh] = *(const float4*)&qkv_b[       h*32 + dh*16 + g*4];
        bk[dh] = *(const float4*)&qkv_b[256 +  h*32 + dh*16 + g*4];
        bv[dh] = qkv_b[512 + h*32 + dh*16 + ln];
    }

    // ---- in-lane repack to bf16 frags (kappa mapping) ----
    s8v qf[4], kf[4], vf[2][2];
    #pragma unroll
    for (int t = 0; t < 4; ++t)
        #pragma unroll
        for (int j = 0; j < 8; ++j) {
            int dh = j >> 2, r = j & 3;
            qf[t][j] = (short)f2bf((qa[dh][t][r] + ((const float*)&bq[dh])[r]) * scale);
            kf[t][j] = (short)f2bf( ka[dh][t][r] + ((const float*)&bk[dh])[r]);
        }
    #pragma unroll
    for (int ksp = 0; ksp < 2; ++ksp)
        #pragma unroll
        for (int dh = 0; dh < 2; ++dh)
            #pragma unroll
            for (int j = 0; j < 8; ++j)
                vf[ksp][dh][j] = (short)f2bf(va[2*ksp + (j>>2)][dh][j & 3] + bv[dh]);

    // ---- attention (per query tile), write O straight to osd ----
    #pragma unroll
    for (int qt = 0; qt < 4; ++qt) {
        f4 st[4];
        #pragma unroll
        for (int kt = 0; kt < 4; ++kt) {
            f4 z = (f4){0.f,0.f,0.f,0.f};
            st[kt] = MFMA(kf[kt], qf[qt], z);
        }
        float pr[16];
        float mx = -3.0e38f;
        #pragma unroll
        for (int kt = 0; kt < 4; ++kt)
            #pragma unroll
            for (int r = 0; r < 4; ++r) {
                float s = st[kt][r] + biasT[(h*64 + kt*16 + g*4 + r)*64 + qt*16 + ln];
                pr[kt*4 + r] = s;
                mx = fmaxf(mx, s);
            }
        mx = fmaxf(mx, __shfl_xor(mx, 16));
        mx = fmaxf(mx, __shfl_xor(mx, 32));
        float sum = 0.f;
        #pragma unroll
        for (int i = 0; i < 16; ++i) {
            float e = __expf(pr[i] - mx);
            pr[i] = e;
            sum += e;
        }
        sum += __shfl_xor(sum, 16);
        sum += __shfl_xor(sum, 32);
        float rinv = 1.f / sum;

        s8v pa[2];
        #pragma unroll
        for (int ksp = 0; ksp < 2; ++ksp)
            #pragma unroll
            for (int j = 0; j < 8; ++j)
                pa[ksp][j] = (short)f2bf(pr[8*ksp + 4*(j>>2) + (j&3)] * rinv);

        f4 oacc[2];
        oacc[0] = (f4){0.f,0.f,0.f,0.f};
        oacc[1] = (f4){0.f,0.f,0.f,0.f};
        #pragma unroll
        for (int ksp = 0; ksp < 2; ++ksp)
            #pragma unroll
            for (int dh = 0; dh < 2; ++dh)
                oacc[dh] = MFMA(pa[ksp], vf[ksp][dh], oacc[dh]);

        #pragma unroll
        for (int dh = 0; dh < 2; ++dh)
            #pragma unroll
            for (int r = 0; r < 4; ++r)
                osd[qt*16 + g*4 + r][h*32 + dh*16 + ln] = f2bf(oacc[dh][r]);
    }
    __syncthreads();

    // ---- proj GEMM: out = O @ Wp + b (2 n-tiles per wave) ----
    f4 acc[4][2];
    #pragma unroll
    for (int mt = 0; mt < 4; ++mt)
        #pragma unroll
        for (int t = 0; t < 2; ++t)
            acc[mt][t] = (f4){0.f,0.f,0.f,0.f};

    #pragma unroll
    for (int ks = 0; ks < 8; ++ks) {
        s8v av[4], bw[2];
        #pragma unroll
        for (int mt = 0; mt < 4; ++mt)
            av[mt] = *(const s8v*)&osd[mt*16 + ln][ks*32 + g*8];
        #pragma unroll
        for (int t = 0; t < 2; ++t) {
            int nt = w*2 + t;
            bw[t] = *(const s8v*)&wp[(size_t)((nt*8 + ks)*64 + lane) * 8];
        }
        #pragma unroll
        for (int mt = 0; mt < 4; ++mt)
            #pragma unroll
            for (int t = 0; t < 2; ++t)
                acc[mt][t] = MFMA(av[mt], bw[t], acc[mt][t]);
    }

    float* ob = out + (size_t)b * (49*256);
    #pragma unroll
    for (int t = 0; t < 2; ++t) {
        int n = (w*2 + t)*16 + ln;
        float pb = proj_b[n];
        #pragma unroll
        for (int mt = 0; mt < 4; ++mt)
            #pragma unroll
            for (int r = 0; r < 4; ++r) {
                int q = mt*16 + g*4 + r;
                if (q < 49)
                    ob[q*256 + n] = acc[mt][t][r] + pb;
            }
    }
}

extern "C" void kernel_launch(void* const* d_in, const int* in_sizes, int n_in,
                              void* d_out, int out_size, void* d_ws, size_t ws_size,
                              hipStream_t stream)
{
    (void)n_in; (void)out_size; (void)ws_size;
    const float* x        = (const float*)d_in[0];
    const int*   rel_idx  = (const int*)  d_in[1];
    const float* qkv_w    = (const float*)d_in[2];
    const float* qkv_b    = (const float*)d_in[3];
    const float* rel_bias = (const float*)d_in[4];
    const float* proj_w   = (const float*)d_in[5];
    const float* proj_b   = (const float*)d_in[6];
    float* out = (float*)d_out;

    const int B = in_sizes[0] / (49*256);

    unsigned short* wq = (unsigned short*)d_ws;                     // 393216 B
    unsigned short* wp = wq + 48*8*64*8;                            // 131072 B
    float* biasT = (float*)((char*)d_ws + 524288);                  // 131072 B

    prep<<<256, 256, 0, stream>>>(qkv_w, proj_w, rel_bias, rel_idx, wq, wp, biasT);
    kall<<<B, 512, 0, stream>>>(x, qkv_b, wq, biasT, wp, proj_b, out);
}